// Round 19
// baseline (101.112 us; speedup 1.0000x reference)
//
#include <hip/hip_runtime.h>

#define HW 16384   // 128*128

typedef __bf16 bf16x8 __attribute__((ext_vector_type(8)));
typedef __bf16 bf16x4 __attribute__((ext_vector_type(4)));
typedef float  f32x4  __attribute__((ext_vector_type(4)));
typedef float  f32x2  __attribute__((ext_vector_type(2)));

// ---------- prep: blocks<512: x -> xt [b][pos][64] + y1 [b][pos][48] (conv1x1 MFMA)
// ----------       blocks>=512 (224): w_t[128][448] bf16 (k = t*48+m, zero-pad)
// No intra-launch race: weight blocks write only wte (consumed by next launch);
// conv1x1 blocks convert wc f32 -> bf16 fragments inline (12 KB, L2-broadcast).
__global__ __launch_bounds__(256, 2)
void prep_fused(const float* __restrict__ x, const float* __restrict__ we,
                const float* __restrict__ wc, const float* __restrict__ bc,
                __bf16* __restrict__ xt, __bf16* __restrict__ y1o,
                __bf16* __restrict__ wt) {
    const int t = threadIdx.x;
    if (blockIdx.x >= 512) {   // ---- encoder-weight transpose part (224 blocks)
        int idx = (blockIdx.x - 512) * 256 + t;   // exactly 128*448
        int e = idx / 448, k = idx % 448;
        float v = 0.f;
        if (e < 100 && k < 432) {
            int tt = k / 48, m = k % 48;
            v = we[(e * 48 + m) * 9 + tt];
        }
        wt[idx] = (__bf16)v;
        return;
    }
    // ---- x transpose + conv1x1 part
    __shared__ __align__(16) float lds[256 * 65];      // 66,560 B
    __bf16* y1s = (__bf16*)lds;                        // [256][56] union (after barrier)

    const int b = blockIdx.x & 7, chunk = blockIdx.x >> 3;   // XCD-pin batch
    const int lane = t & 63, wv = t >> 6;
    const int lgp = lane >> 4, lr = lane & 15;
    const int pos0 = chunk * 256;

    const float* xb = x + (size_t)b * 64 * HW + pos0;
    for (int c = 0; c < 64; ++c)
        lds[t * 65 + c] = xb[(size_t)c * HW + t];
    __syncthreads();

    {   // xt stores (wave-contiguous 2KB)
        const int q = t & 3, pp = t >> 2;
        #pragma unroll
        for (int it = 0; it < 4; ++it) {
            int pos = it * 64 + pp;
            __bf16* o = xt + ((size_t)b * HW + pos0 + pos) * 64 + q * 16;
            bf16x8 v0, v1;
            #pragma unroll
            for (int e = 0; e < 8; ++e) {
                v0[e] = (__bf16)lds[pos * 65 + q * 16 + e];
                v1[e] = (__bf16)lds[pos * 65 + q * 16 + 8 + e];
            }
            *(bf16x8*)o       = v0;
            *(bf16x8*)(o + 8) = v1;
        }
    }
    bf16x8 af[4][2];                       // A-fragments, lane pixel = lr
    #pragma unroll
    for (int i = 0; i < 4; ++i) {
        int pix = (wv * 4 + i) * 16 + lr;
        #pragma unroll
        for (int kc = 0; kc < 2; ++kc)
            #pragma unroll
            for (int e = 0; e < 8; ++e)
                af[i][kc][e] = (__bf16)lds[pix * 65 + kc * 32 + lgp * 8 + e];
    }
    __syncthreads();

    {   // conv1x1 MFMA (swapped: D col = own pixel) -> y1s
        bf16x8 bw[3][2];
        f32x4 bias4[3];
        #pragma unroll
        for (int nt = 0; nt < 3; ++nt) {
            bias4[nt] = *(const f32x4*)(bc + nt * 16 + lgp * 4);
            #pragma unroll
            for (int kc = 0; kc < 2; ++kc) {
                f32x4 w0 = *(const f32x4*)(wc + (nt * 16 + lr) * 64 + kc * 32 + lgp * 8);
                f32x4 w1 = *(const f32x4*)(wc + (nt * 16 + lr) * 64 + kc * 32 + lgp * 8 + 4);
                #pragma unroll
                for (int e = 0; e < 4; ++e) {
                    bw[nt][kc][e]     = (__bf16)w0[e];
                    bw[nt][kc][e + 4] = (__bf16)w1[e];
                }
            }
        }
        #pragma unroll
        for (int i = 0; i < 4; ++i) {
            int pix = (wv * 4 + i) * 16 + lr;
            #pragma unroll
            for (int nt = 0; nt < 3; ++nt) {
                f32x4 cc = bias4[nt];
                cc = __builtin_amdgcn_mfma_f32_16x16x32_bf16(bw[nt][0], af[i][0], cc, 0, 0, 0);
                cc = __builtin_amdgcn_mfma_f32_16x16x32_bf16(bw[nt][1], af[i][1], cc, 0, 0, 0);
                bf16x4 o4;
                #pragma unroll
                for (int r = 0; r < 4; ++r) o4[r] = (__bf16)fmaxf(cc[r], 0.f);
                *(bf16x4*)(y1s + pix * 56 + nt * 16 + lgp * 4) = o4;
            }
        }
    }
    __syncthreads();

    __bf16* yo = y1o + (size_t)(b * HW + pos0) * 48;
    #pragma unroll
    for (int i = 0; i < 6; ++i) {
        int c = i * 256 + t;                     // 1536 chunks of 8 halfwords
        int pix = (c * 10923) >> 16;             // c / 6
        int mc  = c - pix * 6;
        bf16x8 v = *(bf16x8*)(y1s + pix * 56 + mc * 8);
        *(bf16x8*)(yo + (size_t)c * 8) = v;
    }
}

// ---------- fused W+A, tile 8x16 (128 px), 1024 blocks -> 4 blocks/CU ----------
// 256 thr, __launch_bounds__(256,4): VGPR cap 128 (= what the compiler chose at
// cap 256 in R18 -> no spill). LDS union: y1[200][56] 22.4K -> lgt[128][118]
// 30.2K -> lx[240][68] 32.6K; max 32.6K -> 4 blocks/CU, grid 1024 = 4/CU exact.
__global__ __launch_bounds__(256, 4)
void carafe_wa(const __bf16* __restrict__ xt, const __bf16* __restrict__ y1g,
               const __bf16* __restrict__ wt, const float* __restrict__ be,
               float* __restrict__ out) {
    __shared__ __align__(16) char smem[32640];
    __bf16*    y1  = (__bf16*)smem;    // [200][56]  (10x18 halo + K-pad rows)
    _Float16*  lgt = (_Float16*)smem;  // [128][118] (odd-dword stride: conflict-free)
    __bf16*    lx  = (__bf16*)smem;    // [240][68]  (12x20 halo)

    const int tid = threadIdx.x;
    const int lane = tid & 63, wv = tid >> 6;
    const int lgp = lane >> 4, lr = lane & 15;
    const int b = blockIdx.x & 7, tile = blockIdx.x >> 3;    // XCD-pin batch
    const int h0 = (tile >> 3) << 3, w0 = (tile & 7) << 4;   // 16 t-rows x 8 t-cols

    // ===== stage y1 halo (10 rows x 18 cols x 48 ch), zero outside image
    const __bf16* y1b = y1g + (size_t)b * HW * 48;
    #pragma unroll
    for (int it = 0; it < 5; ++it) {
        int id = it * 256 + tid;                 // (hr, wc, mc): 10*18*6 = 1080
        if (id < 1080) {
            int hr  = (id * 607) >> 16;          // id / 108
            int rem = id - hr * 108;
            int wc  = (rem * 10923) >> 16;       // rem / 6
            int mc  = rem - wc * 6;
            int hy = h0 - 1 + hr, wx = w0 - 1 + wc;
            bf16x8 v = {};
            if (hy >= 0 && hy < 128 && wx >= 0 && wx < 128)
                v = *(const bf16x8*)(y1b + (size_t)(hy * 128 + wx) * 48 + mc * 8);
            *(bf16x8*)(y1 + (hr * 18 + wc) * 56 + mc * 8) = v;
        }
    }
    for (int i = tid; i < 1120; i += 256)
        y1[180 * 56 + i] = (__bf16)0.f;          // rows 180..199 (K-pad t=9 reads)
    __syncthreads();

    // ===== P2: logits[128px][112] = Ycol[px][432] * W[432][112], 4 waves x 2 px-tiles
    f32x4 acc[2][7];
    #pragma unroll
    for (int ot = 0; ot < 7; ++ot) {
        int o_ = ot * 16 + lr;
        float bz = (o_ < 100) ? be[o_] : 0.f;
        #pragma unroll
        for (int i = 0; i < 2; ++i) acc[i][ot] = {bz, bz, bz, bz};
    }
    const int ptg0 = wv * 2;   // pixel-tile row == tile index (tw=16)

    auto ldA = [&](bf16x8 A[2], int kc) {
        int Kb = kc * 32 + lgp * 8;
        int t  = (Kb * 683) >> 15;  int m0 = Kb - t * 48;   // k = t*48+m
        int ty = (t * 11) >> 5;     int tx = t - ty * 3;
        int base = ty * 18 + lr + tx;
        #pragma unroll
        for (int i = 0; i < 2; ++i)
            A[i] = *(const bf16x8*)(y1 + ((ptg0 + i) * 18 + base) * 56 + m0);
    };
    auto ldB = [&](bf16x8 B[7], int kc) {
        #pragma unroll
        for (int j = 0; j < 7; ++j)
            B[j] = *(const bf16x8*)(wt + (j * 16 + lr) * 448 + kc * 32 + lgp * 8);
    };
    auto mm = [&](bf16x8 A[2], bf16x8 B[7]) {
        #pragma unroll
        for (int i = 0; i < 2; ++i)
            #pragma unroll
            for (int j = 0; j < 7; ++j)
                acc[i][j] = __builtin_amdgcn_mfma_f32_16x16x32_bf16(A[i], B[j], acc[i][j], 0, 0, 0);
    };

    bf16x8 A0[2], B0[7], A1[2], B1[7];
    ldA(A0, 0); ldB(B0, 0);
    #pragma unroll
    for (int kc = 0; kc < 14; kc += 2) {
        if (kc + 1 < 14) { ldA(A1, kc + 1); ldB(B1, kc + 1); }
        mm(A0, B0);
        if (kc + 2 < 14) { ldA(A0, kc + 2); ldB(B0, kc + 2); }
        if (kc + 1 < 14) mm(A1, B1);
    }
    __syncthreads();   // y1 dead

    // ===== spill logits to LDS [128][118] fp16
    #pragma unroll
    for (int i = 0; i < 2; ++i)
        #pragma unroll
        for (int j = 0; j < 7; ++j) {
            int o_ = j * 16 + lr;
            #pragma unroll
            for (int r = 0; r < 4; ++r) {
                int p = (ptg0 + i) * 16 + lgp * 4 + r;
                lgt[p * 118 + o_] = (_Float16)acc[i][j][r];
            }
        }

    // ===== T14: issue x-halo loads NOW (latency hides under barrier + softmax)
    bf16x8 hv[8];
    #pragma unroll
    for (int it = 0; it < 8; ++it) {
        int id = it * 256 + tid;                 // 240 pos x 8 ch-chunks = 1920
        bf16x8 v = {};
        if (id < 1920) {
            int pos = id >> 3, l8 = id & 7;
            int r = (pos * 3277) >> 16;          // pos / 20
            int q = pos - r * 20;
            int hy = h0 - 2 + r, wx = w0 - 2 + q;
            if (hy >= 0 && hy < 128 && wx >= 0 && wx < 128)
                v = *(const bf16x8*)(xt + ((size_t)b * HW + hy * 128 + wx) * 64 + l8 * 8);
        }
        hv[it] = v;
    }
    __syncthreads();   // lgt visible

    // ===== softmax(25) x2 groups (sgrp pair) -> wt_[50] regs
    const int pix = tid & 127, sgrp = tid >> 7;
    const int py = pix >> 4, px = pix & 15;
    const int h = h0 + py, w = w0 + px;
    float wt_[50];
    {
        const _Float16* lrow = lgt + pix * 118 + sgrp * 50;
        #pragma unroll
        for (int g = 0; g < 2; ++g) {
            float* v = wt_ + g * 25;
            #pragma unroll
            for (int k = 0; k < 25; ++k) v[k] = (float)lrow[g * 25 + k];
            float mx = v[0];
            #pragma unroll
            for (int k = 1; k < 25; ++k) mx = fmaxf(mx, v[k]);
            float s = 0.f;
            #pragma unroll
            for (int k = 0; k < 25; ++k) { v[k] = __expf(v[k] - mx); s += v[k]; }
            float inv = 1.f / s;
            #pragma unroll
            for (int k = 0; k < 25; ++k) v[k] *= inv;
        }
    }
    __syncthreads();   // all lgt reads done; lx may overwrite

    // ===== stage x halo from in-flight regs
    #pragma unroll
    for (int it = 0; it < 8; ++it) {
        int id = it * 256 + tid;
        if (id < 1920) {
            int pos = id >> 3, l8 = id & 7;
            bf16x4 vlo = {hv[it][0], hv[it][1], hv[it][2], hv[it][3]};
            bf16x4 vhi = {hv[it][4], hv[it][5], hv[it][6], hv[it][7]};
            *(bf16x4*)(lx + pos * 68 + l8 * 8)     = vlo;
            *(bf16x4*)(lx + pos * 68 + l8 * 8 + 4) = vhi;
        }
    }
    __syncthreads();

    // ===== 5x5 weighted gather from LDS + pixel shuffle (NT stores, 128B lines)
    float* ob = out + (size_t)b * 256 * HW;
    #pragma unroll 1
    for (int cq = 0; cq < 16; ++cq) {          // channels c = 4*cq .. 4*cq+3
        f32x2 a0 = {0.f, 0.f}, a1 = {0.f, 0.f}, a2 = {0.f, 0.f}, a3 = {0.f, 0.f};
        #pragma unroll
        for (int ki = 0; ki < 5; ++ki) {
            const int rowbase = (py + ki) * 20 + px;
            #pragma unroll
            for (int kj = 0; kj < 5; ++kj) {
                uint2 u = *(const uint2*)(lx + (rowbase + kj) * 68 + cq * 4);
                f32x2 xlo = { __uint_as_float(u.x << 16), __uint_as_float(u.x & 0xffff0000u) };
                f32x2 xhi = { __uint_as_float(u.y << 16), __uint_as_float(u.y & 0xffff0000u) };
                float wA = wt_[ki * 5 + kj];
                float wB = wt_[25 + ki * 5 + kj];
                a0 += xlo * wA;
                a1 += xhi * wA;
                a2 += xlo * wB;
                a3 += xhi * wB;
            }
        }
        // ch C = s*64 + 4cq + d -> plane q = s*16+cq, (r1,r2) = (d>>1, d&1); s = 2sgrp{+1}
        size_t base0 = ((size_t)(sgrp * 32 + cq) * 256 + 2 * h) * 256 + 2 * w;
        size_t base1 = base0 + (size_t)16 * 256 * 256;
        __builtin_nontemporal_store(a0, (f32x2*)(ob + base0));
        __builtin_nontemporal_store(a1, (f32x2*)(ob + base0 + 256));
        __builtin_nontemporal_store(a2, (f32x2*)(ob + base1));
        __builtin_nontemporal_store(a3, (f32x2*)(ob + base1 + 256));
    }
}

extern "C" void kernel_launch(void* const* d_in, const int* in_sizes, int n_in,
                              void* d_out, int out_size, void* d_ws, size_t ws_size,
                              hipStream_t stream) {
    const float* x  = (const float*)d_in[0];   // [8][64][128][128]
    const float* wc = (const float*)d_in[1];   // [48][64]
    const float* bc = (const float*)d_in[2];   // [48]
    const float* we = (const float*)d_in[3];   // [100][48][3][3]
    const float* be = (const float*)d_in[4];   // [100]
    float* out = (float*)d_out;                // [8][64][256][256]

    // ws: xt 16,777,216 | y1 25,165,824 | wte 114,688
    __bf16* xt  = (__bf16*)d_ws;
    __bf16* y1g = (__bf16*)((char*)d_ws + 16777216);
    __bf16* wte = (__bf16*)((char*)d_ws + 41943040);

    prep_fused<<<512 + 224, 256, 0, stream>>>(x, we, wc, bc, xt, y1g, wte);
    carafe_wa<<<1024, 256, 0, stream>>>(xt, y1g, wte, be, out);
}

// Round 20
// 89.378 us; speedup vs baseline: 1.1313x; 1.1313x over previous
//
#include <hip/hip_runtime.h>

#define HW 16384   // 128*128

typedef __bf16 bf16x8 __attribute__((ext_vector_type(8)));
typedef __bf16 bf16x4 __attribute__((ext_vector_type(4)));
typedef float  f32x4  __attribute__((ext_vector_type(4)));
typedef float  f32x2  __attribute__((ext_vector_type(2)));

// ---------- prep: blocks<512: x -> xt [b][pos][64] + y1 [b][pos][48] (conv1x1 MFMA)
// ----------       blocks>=512 (224): w_t[128][448] bf16 (k = t*48+m, zero-pad)
__global__ __launch_bounds__(256, 2)
void prep_fused(const float* __restrict__ x, const float* __restrict__ we,
                const float* __restrict__ wc, const float* __restrict__ bc,
                __bf16* __restrict__ xt, __bf16* __restrict__ y1o,
                __bf16* __restrict__ wt) {
    const int t = threadIdx.x;
    if (blockIdx.x >= 512) {   // ---- encoder-weight transpose part (224 blocks)
        int idx = (blockIdx.x - 512) * 256 + t;   // exactly 128*448
        int e = idx / 448, k = idx % 448;
        float v = 0.f;
        if (e < 100 && k < 432) {
            int tt = k / 48, m = k % 48;
            v = we[(e * 48 + m) * 9 + tt];
        }
        wt[idx] = (__bf16)v;
        return;
    }
    // ---- x transpose + conv1x1 part
    __shared__ __align__(16) float lds[256 * 65];      // 66,560 B
    __bf16* y1s = (__bf16*)lds;                        // [256][56] union (after barrier)

    const int b = blockIdx.x & 7, chunk = blockIdx.x >> 3;   // XCD-pin batch
    const int lane = t & 63, wv = t >> 6;
    const int lgp = lane >> 4, lr = lane & 15;
    const int pos0 = chunk * 256;

    const float* xb = x + (size_t)b * 64 * HW + pos0;
    for (int c = 0; c < 64; ++c)
        lds[t * 65 + c] = xb[(size_t)c * HW + t];
    __syncthreads();

    {   // xt stores (wave-contiguous 2KB)
        const int q = t & 3, pp = t >> 2;
        #pragma unroll
        for (int it = 0; it < 4; ++it) {
            int pos = it * 64 + pp;
            __bf16* o = xt + ((size_t)b * HW + pos0 + pos) * 64 + q * 16;
            bf16x8 v0, v1;
            #pragma unroll
            for (int e = 0; e < 8; ++e) {
                v0[e] = (__bf16)lds[pos * 65 + q * 16 + e];
                v1[e] = (__bf16)lds[pos * 65 + q * 16 + 8 + e];
            }
            *(bf16x8*)o       = v0;
            *(bf16x8*)(o + 8) = v1;
        }
    }
    bf16x8 af[4][2];                       // A-fragments, lane pixel = lr
    #pragma unroll
    for (int i = 0; i < 4; ++i) {
        int pix = (wv * 4 + i) * 16 + lr;
        #pragma unroll
        for (int kc = 0; kc < 2; ++kc)
            #pragma unroll
            for (int e = 0; e < 8; ++e)
                af[i][kc][e] = (__bf16)lds[pix * 65 + kc * 32 + lgp * 8 + e];
    }
    __syncthreads();

    {   // conv1x1 MFMA (swapped: D col = own pixel) -> y1s
        bf16x8 bw[3][2];
        f32x4 bias4[3];
        #pragma unroll
        for (int nt = 0; nt < 3; ++nt) {
            bias4[nt] = *(const f32x4*)(bc + nt * 16 + lgp * 4);
            #pragma unroll
            for (int kc = 0; kc < 2; ++kc) {
                f32x4 w0 = *(const f32x4*)(wc + (nt * 16 + lr) * 64 + kc * 32 + lgp * 8);
                f32x4 w1 = *(const f32x4*)(wc + (nt * 16 + lr) * 64 + kc * 32 + lgp * 8 + 4);
                #pragma unroll
                for (int e = 0; e < 4; ++e) {
                    bw[nt][kc][e]     = (__bf16)w0[e];
                    bw[nt][kc][e + 4] = (__bf16)w1[e];
                }
            }
        }
        #pragma unroll
        for (int i = 0; i < 4; ++i) {
            int pix = (wv * 4 + i) * 16 + lr;
            #pragma unroll
            for (int nt = 0; nt < 3; ++nt) {
                f32x4 cc = bias4[nt];
                cc = __builtin_amdgcn_mfma_f32_16x16x32_bf16(bw[nt][0], af[i][0], cc, 0, 0, 0);
                cc = __builtin_amdgcn_mfma_f32_16x16x32_bf16(bw[nt][1], af[i][1], cc, 0, 0, 0);
                bf16x4 o4;
                #pragma unroll
                for (int r = 0; r < 4; ++r) o4[r] = (__bf16)fmaxf(cc[r], 0.f);
                *(bf16x4*)(y1s + pix * 56 + nt * 16 + lgp * 4) = o4;
            }
        }
    }
    __syncthreads();

    __bf16* yo = y1o + (size_t)(b * HW + pos0) * 48;
    #pragma unroll
    for (int i = 0; i < 6; ++i) {
        int c = i * 256 + t;                     // 1536 chunks of 8 halfwords
        int pix = (c * 10923) >> 16;             // c / 6
        int mc  = c - pix * 6;
        bf16x8 v = *(bf16x8*)(y1s + pix * 56 + mc * 8);
        *(bf16x8*)(yo + (size_t)c * 8) = v;
    }
}

// ---------- fused W+A, tile 8x16 (128 px), 1024 blocks ----------
// __launch_bounds__(256, 2): VGPR cap 128 — R19's (256,4) forced VGPR=64 and
// spilled (~22MB scratch writes, 96us). At VGPR<=128 the HW still allows
// 4 waves/SIMD, and LDS 32.6KB <= 40KB allows 4 blocks/CU — we get the
// intended residency WITHOUT the spill.
// LDS union: y1[200][56] 22.4K -> lgt[128][118] 30.2K -> lx[240][68] 32.6K
__global__ __launch_bounds__(256, 2)
void carafe_wa(const __bf16* __restrict__ xt, const __bf16* __restrict__ y1g,
               const __bf16* __restrict__ wt, const float* __restrict__ be,
               float* __restrict__ out) {
    __shared__ __align__(16) char smem[32640];
    __bf16*    y1  = (__bf16*)smem;    // [200][56]  (10x18 halo + K-pad rows)
    _Float16*  lgt = (_Float16*)smem;  // [128][118] (odd-dword stride: conflict-free)
    __bf16*    lx  = (__bf16*)smem;    // [240][68]  (12x20 halo)

    const int tid = threadIdx.x;
    const int lane = tid & 63, wv = tid >> 6;
    const int lgp = lane >> 4, lr = lane & 15;
    const int b = blockIdx.x & 7, tile = blockIdx.x >> 3;    // XCD-pin batch
    const int h0 = (tile >> 3) << 3, w0 = (tile & 7) << 4;   // 16 t-rows x 8 t-cols

    // ===== stage y1 halo (10 rows x 18 cols x 48 ch), zero outside image
    const __bf16* y1b = y1g + (size_t)b * HW * 48;
    #pragma unroll
    for (int it = 0; it < 5; ++it) {
        int id = it * 256 + tid;                 // (hr, wc, mc): 10*18*6 = 1080
        if (id < 1080) {
            int hr  = (id * 607) >> 16;          // id / 108
            int rem = id - hr * 108;
            int wc  = (rem * 10923) >> 16;       // rem / 6
            int mc  = rem - wc * 6;
            int hy = h0 - 1 + hr, wx = w0 - 1 + wc;
            bf16x8 v = {};
            if (hy >= 0 && hy < 128 && wx >= 0 && wx < 128)
                v = *(const bf16x8*)(y1b + (size_t)(hy * 128 + wx) * 48 + mc * 8);
            *(bf16x8*)(y1 + (hr * 18 + wc) * 56 + mc * 8) = v;
        }
    }
    for (int i = tid; i < 1120; i += 256)
        y1[180 * 56 + i] = (__bf16)0.f;          // rows 180..199 (K-pad t=9 reads)
    __syncthreads();

    // ===== P2: logits[128px][112] = Ycol[px][432] * W[432][112], 4 waves x 2 px-tiles
    f32x4 acc[2][7];
    #pragma unroll
    for (int ot = 0; ot < 7; ++ot) {
        int o_ = ot * 16 + lr;
        float bz = (o_ < 100) ? be[o_] : 0.f;
        #pragma unroll
        for (int i = 0; i < 2; ++i) acc[i][ot] = {bz, bz, bz, bz};
    }
    const int ptg0 = wv * 2;

    auto ldA = [&](bf16x8 A[2], int kc) {
        int Kb = kc * 32 + lgp * 8;
        int t  = (Kb * 683) >> 15;  int m0 = Kb - t * 48;   // k = t*48+m
        int ty = (t * 11) >> 5;     int tx = t - ty * 3;
        int base = ty * 18 + lr + tx;
        #pragma unroll
        for (int i = 0; i < 2; ++i)
            A[i] = *(const bf16x8*)(y1 + ((ptg0 + i) * 18 + base) * 56 + m0);
    };
    auto ldB = [&](bf16x8 B[7], int kc) {
        #pragma unroll
        for (int j = 0; j < 7; ++j)
            B[j] = *(const bf16x8*)(wt + (j * 16 + lr) * 448 + kc * 32 + lgp * 8);
    };
    auto mm = [&](bf16x8 A[2], bf16x8 B[7]) {
        #pragma unroll
        for (int i = 0; i < 2; ++i)
            #pragma unroll
            for (int j = 0; j < 7; ++j)
                acc[i][j] = __builtin_amdgcn_mfma_f32_16x16x32_bf16(A[i], B[j], acc[i][j], 0, 0, 0);
    };

    bf16x8 A0[2], B0[7], A1[2], B1[7];
    ldA(A0, 0); ldB(B0, 0);
    #pragma unroll
    for (int kc = 0; kc < 14; kc += 2) {
        if (kc + 1 < 14) { ldA(A1, kc + 1); ldB(B1, kc + 1); }
        mm(A0, B0);
        if (kc + 2 < 14) { ldA(A0, kc + 2); ldB(B0, kc + 2); }
        if (kc + 1 < 14) mm(A1, B1);
    }
    __syncthreads();   // y1 dead

    // ===== spill logits to LDS [128][118] fp16
    #pragma unroll
    for (int i = 0; i < 2; ++i)
        #pragma unroll
        for (int j = 0; j < 7; ++j) {
            int o_ = j * 16 + lr;
            #pragma unroll
            for (int r = 0; r < 4; ++r) {
                int p = (ptg0 + i) * 16 + lgp * 4 + r;
                lgt[p * 118 + o_] = (_Float16)acc[i][j][r];
            }
        }

    // ===== T14: issue x-halo loads NOW (latency hides under barrier + softmax)
    bf16x8 hv[8];
    #pragma unroll
    for (int it = 0; it < 8; ++it) {
        int id = it * 256 + tid;                 // 240 pos x 8 ch-chunks = 1920
        bf16x8 v = {};
        if (id < 1920) {
            int pos = id >> 3, l8 = id & 7;
            int r = (pos * 3277) >> 16;          // pos / 20
            int q = pos - r * 20;
            int hy = h0 - 2 + r, wx = w0 - 2 + q;
            if (hy >= 0 && hy < 128 && wx >= 0 && wx < 128)
                v = *(const bf16x8*)(xt + ((size_t)b * HW + hy * 128 + wx) * 64 + l8 * 8);
        }
        hv[it] = v;
    }
    __syncthreads();   // lgt visible

    // ===== softmax(25) x2 groups (sgrp pair) -> wt_[50] regs
    const int pix = tid & 127, sgrp = tid >> 7;
    const int py = pix >> 4, px = pix & 15;
    const int h = h0 + py, w = w0 + px;
    float wt_[50];
    {
        const _Float16* lrow = lgt + pix * 118 + sgrp * 50;
        #pragma unroll
        for (int g = 0; g < 2; ++g) {
            float* v = wt_ + g * 25;
            #pragma unroll
            for (int k = 0; k < 25; ++k) v[k] = (float)lrow[g * 25 + k];
            float mx = v[0];
            #pragma unroll
            for (int k = 1; k < 25; ++k) mx = fmaxf(mx, v[k]);
            float s = 0.f;
            #pragma unroll
            for (int k = 0; k < 25; ++k) { v[k] = __expf(v[k] - mx); s += v[k]; }
            float inv = 1.f / s;
            #pragma unroll
            for (int k = 0; k < 25; ++k) v[k] *= inv;
        }
    }
    __syncthreads();   // all lgt reads done; lx may overwrite

    // ===== stage x halo from in-flight regs
    #pragma unroll
    for (int it = 0; it < 8; ++it) {
        int id = it * 256 + tid;
        if (id < 1920) {
            int pos = id >> 3, l8 = id & 7;
            bf16x4 vlo = {hv[it][0], hv[it][1], hv[it][2], hv[it][3]};
            bf16x4 vhi = {hv[it][4], hv[it][5], hv[it][6], hv[it][7]};
            *(bf16x4*)(lx + pos * 68 + l8 * 8)     = vlo;
            *(bf16x4*)(lx + pos * 68 + l8 * 8 + 4) = vhi;
        }
    }
    __syncthreads();

    // ===== 5x5 weighted gather from LDS + pixel shuffle (NT stores, 128B lines)
    float* ob = out + (size_t)b * 256 * HW;
    #pragma unroll 1
    for (int cq = 0; cq < 16; ++cq) {          // channels c = 4*cq .. 4*cq+3
        f32x2 a0 = {0.f, 0.f}, a1 = {0.f, 0.f}, a2 = {0.f, 0.f}, a3 = {0.f, 0.f};
        #pragma unroll
        for (int ki = 0; ki < 5; ++ki) {
            const int rowbase = (py + ki) * 20 + px;
            #pragma unroll
            for (int kj = 0; kj < 5; ++kj) {
                uint2 u = *(const uint2*)(lx + (rowbase + kj) * 68 + cq * 4);
                f32x2 xlo = { __uint_as_float(u.x << 16), __uint_as_float(u.x & 0xffff0000u) };
                f32x2 xhi = { __uint_as_float(u.y << 16), __uint_as_float(u.y & 0xffff0000u) };
                float wA = wt_[ki * 5 + kj];
                float wB = wt_[25 + ki * 5 + kj];
                a0 += xlo * wA;
                a1 += xhi * wA;
                a2 += xlo * wB;
                a3 += xhi * wB;
            }
        }
        // ch C = s*64 + 4cq + d -> plane q = s*16+cq, (r1,r2) = (d>>1, d&1); s = 2sgrp{+1}
        size_t base0 = ((size_t)(sgrp * 32 + cq) * 256 + 2 * h) * 256 + 2 * w;
        size_t base1 = base0 + (size_t)16 * 256 * 256;
        __builtin_nontemporal_store(a0, (f32x2*)(ob + base0));
        __builtin_nontemporal_store(a1, (f32x2*)(ob + base0 + 256));
        __builtin_nontemporal_store(a2, (f32x2*)(ob + base1));
        __builtin_nontemporal_store(a3, (f32x2*)(ob + base1 + 256));
    }
}

extern "C" void kernel_launch(void* const* d_in, const int* in_sizes, int n_in,
                              void* d_out, int out_size, void* d_ws, size_t ws_size,
                              hipStream_t stream) {
    const float* x  = (const float*)d_in[0];   // [8][64][128][128]
    const float* wc = (const float*)d_in[1];   // [48][64]
    const float* bc = (const float*)d_in[2];   // [48]
    const float* we = (const float*)d_in[3];   // [100][48][3][3]
    const float* be = (const float*)d_in[4];   // [100]
    float* out = (float*)d_out;                // [8][64][256][256]

    // ws: xt 16,777,216 | y1 25,165,824 | wte 114,688
    __bf16* xt  = (__bf16*)d_ws;
    __bf16* y1g = (__bf16*)((char*)d_ws + 16777216);
    __bf16* wte = (__bf16*)((char*)d_ws + 41943040);

    prep_fused<<<512 + 224, 256, 0, stream>>>(x, we, wc, bc, xt, y1g, wte);
    carafe_wa<<<1024, 256, 0, stream>>>(xt, y1g, wte, be, out);
}